// Round 3
// baseline (1960.473 us; speedup 1.0000x reference)
//
#include <hip/hip_runtime.h>
#include <hip/hip_bf16.h>

// CAGAT_MinSum_Layer_Lite — per-XCD replicated accumulators with L2-local atomics.
//
// Evidence trail:
//  R1: device-scope fp32 atomicAdd = 20.6 G ops/s ceiling at the memory fabric
//      (WRITE_SIZE = 33.5M x 32 B; VALUBusy 1.3%). Scatter-adds bypass the
//      non-coherent per-XCD L2s when device-scoped.
//  R2: two-phase partition just moved the random scatter to 8 B records
//      (FETCH 1.86 GB from partial-line RMW) — scatter granularity is the bug.
//
// Fix: output (4 MB) fits in ONE XCD's 4 MB L2. Keep 8 replicas (one per XCD),
// resolve the physical XCD via s_getreg(HW_REG_XCC_ID) [learn_hip m09], and use
// WORKGROUP-scope atomic fadd so the RMW executes in the local XCD L2 (vector
// atomics always execute in L2, never the non-coherent L1, so same-XCD blocks
// are mutually coherent). Only XCD k touches replica k -> no cross-XCD aliasing.
// End-of-dispatch release flushes L2s; a second kernel sums the 8 replicas.

#define THREADS 256
#define NREP    8

__device__ __forceinline__ unsigned xcc_id() {
    unsigned x;
    asm volatile("s_getreg_b32 %0, hwreg(HW_REG_XCC_ID, 0, 32)" : "=s"(x));
    return x & (NREP - 1u);
}

__device__ __forceinline__ float edge_msg(float xs, float xd, float cc,
                                          float W0, float W1, float W2,
                                          float bb, float ms, float cp) {
    float raw = fmaf(xs, W0, fmaf(xd, W1, fmaf(cc, W2, bb)));
    raw = (raw > 0.0f) ? raw : 0.01f * raw;            // leaky_relu
    raw = fmaf(cc, cp, raw);
    const float att = __builtin_amdgcn_rcpf(1.0f + __expf(-raw));  // sigmoid
    return xs * att * ms;
}

__global__ __launch_bounds__(THREADS) void cagat_xcd_atomic(
    const float* __restrict__ nf,
    const int*   __restrict__ srcs,
    const int*   __restrict__ dsts,
    const float* __restrict__ cm,
    const float* __restrict__ Wp, const float* __restrict__ bp,
    const float* __restrict__ msp, const float* __restrict__ cpp_,
    float* __restrict__ reps,      // [NREP, N] zeroed
    int N, int E)
{
    const float W0 = Wp[0], W1 = Wp[1], W2 = Wp[2];
    const float bb = bp[0], ms = msp[0], cp = cpp_[0];

    float* rep = reps + (size_t)xcc_id() * (size_t)N;

    const int nvec   = E >> 2;
    const int stride = gridDim.x * blockDim.x;
    for (int i = blockIdx.x * blockDim.x + threadIdx.x; i < nvec; i += stride) {
        const int base = i << 2;
        const int4   s4 = *(const int4*)  (srcs + base);
        const int4   d4 = *(const int4*)  (dsts + base);
        const float4 c4 = *(const float4*)(cm   + base);
        const int   s[4] = {s4.x, s4.y, s4.z, s4.w};
        const int   d[4] = {d4.x, d4.y, d4.z, d4.w};
        const float c[4] = {c4.x, c4.y, c4.z, c4.w};
#pragma unroll
        for (int k = 0; k < 4; ++k) {
            const float msg = edge_msg(nf[s[k]], nf[d[k]], c[k], W0, W1, W2, bb, ms, cp);
            __hip_atomic_fetch_add(rep + d[k], msg, __ATOMIC_RELAXED,
                                   __HIP_MEMORY_SCOPE_WORKGROUP);
        }
    }
    // tail (E % 4, normally empty for E=2^25)
    if (blockIdx.x == 0) {
        for (int e = (nvec << 2) + threadIdx.x; e < E; e += THREADS) {
            const float msg = edge_msg(nf[srcs[e]], nf[dsts[e]], cm[e],
                                       W0, W1, W2, bb, ms, cp);
            __hip_atomic_fetch_add(rep + dsts[e], msg, __ATOMIC_RELAXED,
                                   __HIP_MEMORY_SCOPE_WORKGROUP);
        }
    }
}

__global__ __launch_bounds__(THREADS) void cagat_reduce_reps(
    const float* __restrict__ reps, float* __restrict__ out, int N)
{
    const int i  = blockIdx.x * blockDim.x + threadIdx.x;
    const int b4 = i << 2;
    if (b4 + 3 < N) {
        float4 acc = *(const float4*)(reps + b4);
#pragma unroll
        for (int r = 1; r < NREP; ++r) {
            const float4 v = *(const float4*)(reps + (size_t)r * N + b4);
            acc.x += v.x; acc.y += v.y; acc.z += v.z; acc.w += v.w;
        }
        *(float4*)(out + b4) = acc;
    } else if (b4 < N) {
        for (int j = b4; j < N; ++j) {
            float a = 0.0f;
#pragma unroll
            for (int r = 0; r < NREP; ++r) a += reps[(size_t)r * N + j];
            out[j] = a;
        }
    }
}

// ---- proven fallback (round-1 kernel) if ws is too small ----
__global__ __launch_bounds__(THREADS) void cagat_atomic_fallback(
    const float* __restrict__ nf, const int* __restrict__ srcs,
    const int* __restrict__ dsts, const float* __restrict__ cm,
    const float* __restrict__ Wp, const float* __restrict__ bp,
    const float* __restrict__ msp, const float* __restrict__ cpp_,
    float* __restrict__ out, int E)
{
    const float W0 = Wp[0], W1 = Wp[1], W2 = Wp[2];
    const float bb = bp[0], ms = msp[0], cp = cpp_[0];
    const int i = blockIdx.x * blockDim.x + threadIdx.x;
    for (int e = i; e < E; e += gridDim.x * blockDim.x) {
        const float msg = edge_msg(nf[srcs[e]], nf[dsts[e]], cm[e],
                                   W0, W1, W2, bb, ms, cp);
        atomicAdd(out + dsts[e], msg);
    }
}

extern "C" void kernel_launch(void* const* d_in, const int* in_sizes, int n_in,
                              void* d_out, int out_size, void* d_ws, size_t ws_size,
                              hipStream_t stream) {
    const float* nf   = (const float*)d_in[0];
    const int*   eidx = (const int*)  d_in[1];   // [2, E]: src row then dst row
    const float* cm   = (const float*)d_in[2];
    const float* W    = (const float*)d_in[3];
    const float* b    = (const float*)d_in[4];
    const float* ms   = (const float*)d_in[5];
    const float* cp   = (const float*)d_in[6];
    float*       out  = (float*)d_out;

    const int E = in_sizes[2];
    const int N = in_sizes[0];
    const int* srcs = eidx;
    const int* dsts = eidx + E;

    const size_t rep_bytes = (size_t)NREP * (size_t)N * sizeof(float);

    if (ws_size < rep_bytes) {
        hipMemsetAsync(d_out, 0, (size_t)out_size * sizeof(float), stream);
        cagat_atomic_fallback<<<8192, THREADS, 0, stream>>>(
            nf, srcs, dsts, cm, W, b, ms, cp, out, E);
        return;
    }

    float* reps = (float*)d_ws;
    hipMemsetAsync(d_ws, 0, rep_bytes, stream);   // ws is poisoned 0xAA each call

    cagat_xcd_atomic<<<8192, THREADS, 0, stream>>>(
        nf, srcs, dsts, cm, W, b, ms, cp, reps, N, E);

    const int nred = (N + 4 * THREADS - 1) / (4 * THREADS);
    cagat_reduce_reps<<<nred, THREADS, 0, stream>>>(reps, out, N);
}

// Round 4
// 1086.561 us; speedup vs baseline: 1.8043x; 1.8043x over previous
//
#include <hip/hip_runtime.h>
#include <hip/hip_bf16.h>

// CAGAT_MinSum_Layer_Lite — radix partition with LDS tile-permute + sliced reduce.
//
// Evidence trail:
//  R1/R3: global fp32 atomicAdd executes at the memory fabric REGARDLESS of
//         scope (WRITE = 33.5M x 32 B both rounds) -> ~20.6 G atomics/s hard
//         ceiling. Any global-atomic formulation is dead.
//  R2:    partition was right, but per-record 8 B scatter cost 1.86 GB FETCH /
//         0.97 GB WRITE (partial-line RMW). Fix the WRITE PATTERN:
//         per-tile LDS counting-sort so copy-out is linear (avg 256 B runs).
//
// P1   : per-block bucket histogram (bucket = dst>>13, 128 buckets)
// scan1: per-bucket exclusive prefix over blocks (in place)
// scan2: exclusive prefix of bucket totals
// P2   : per 4096-edge tile: LDS hist -> scan -> rank -> permute -> coalesced
//        copy-out of (msg,dst) records to exact global slots. No global atomics.
// P3   : bucket x 4 slices; coalesced record read -> 32 KB LDS fp32 accumulate
//        -> partial accumulator store (everything overwritten; poison-safe)
// P4   : sum 4 partials -> out

#define THREADS 256
#define NBLK    1024            // P1/P2 partition blocks
#define NBUCK   128             // buckets
#define BSH     13              // bucket = dst >> 13  (8192 nodes/bucket)
#define NPB     (1 << BSH)      // nodes per bucket
#define TILE    4096            // edges per P2 tile (32 KB LDS record buffer)
#define NSLICE  4               // P3 slices per bucket
#define NPAD    (NBUCK << BSH)  // padded node space = 1048576

__device__ __forceinline__ float edge_msg(float xs, float xd, float cc,
                                          float W0, float W1, float W2,
                                          float bb, float ms, float cp) {
    float raw = fmaf(xs, W0, fmaf(xd, W1, fmaf(cc, W2, bb)));
    raw = (raw > 0.0f) ? raw : 0.01f * raw;            // leaky_relu
    raw = fmaf(cc, cp, raw);
    const float att = __builtin_amdgcn_rcpf(1.0f + __expf(-raw));  // sigmoid
    return xs * att * ms;
}

__global__ __launch_bounds__(THREADS) void p1_hist(
    const int* __restrict__ dsts, int E, int epb,
    unsigned int* __restrict__ histT)
{
    __shared__ unsigned int h[NBUCK];
    if (threadIdx.x < NBUCK) h[threadIdx.x] = 0u;
    __syncthreads();

    const int blk   = blockIdx.x;
    const int start = blk * epb;
    const int end   = min(E, start + epb);
    const int n     = end - start;
    const int nvec  = n >> 2;

    for (int i = threadIdx.x; i < nvec; i += THREADS) {
        const int4 d4 = *(const int4*)(dsts + start + (i << 2));
        atomicAdd(&h[d4.x >> BSH], 1u);
        atomicAdd(&h[d4.y >> BSH], 1u);
        atomicAdd(&h[d4.z >> BSH], 1u);
        atomicAdd(&h[d4.w >> BSH], 1u);
    }
    for (int e = start + (nvec << 2) + threadIdx.x; e < end; e += THREADS)
        atomicAdd(&h[dsts[e] >> BSH], 1u);

    __syncthreads();
    if (threadIdx.x < NBUCK)
        histT[(size_t)threadIdx.x * NBLK + blk] = h[threadIdx.x];
}

// one block per bucket: exclusive prefix over its NBLK counts, in place
__global__ __launch_bounds__(THREADS) void p_scan1(
    unsigned int* __restrict__ histT, unsigned int* __restrict__ totals)
{
    const int b = blockIdx.x;
    unsigned int* row = histT + (size_t)b * NBLK;
    const int t = threadIdx.x;

    uint4 c = *(uint4*)(row + (t << 2));      // NBLK = 256*4
    const unsigned s1 = c.x;
    const unsigned s2 = c.x + c.y;
    const unsigned s3 = s2 + c.z;
    const unsigned tsum = s3 + c.w;

    __shared__ unsigned int ls[THREADS];
    ls[t] = tsum;
    __syncthreads();
    for (int off = 1; off < THREADS; off <<= 1) {
        unsigned tmp = 0u;
        if (t >= off) tmp = ls[t - off];
        __syncthreads();
        if (t >= off) ls[t] += tmp;
        __syncthreads();
    }
    const unsigned base = (t == 0) ? 0u : ls[t - 1];

    uint4 o;
    o.x = base; o.y = base + s1; o.z = base + s2; o.w = base + s3;
    *(uint4*)(row + (t << 2)) = o;
    if (t == 0) totals[b] = ls[THREADS - 1];
}

__global__ __launch_bounds__(NBUCK) void p_scan2(
    const unsigned int* __restrict__ totals, unsigned int* __restrict__ bucketBase)
{
    __shared__ unsigned int ls[NBUCK];
    const int t = threadIdx.x;
    ls[t] = totals[t];
    __syncthreads();
    for (int off = 1; off < NBUCK; off <<= 1) {
        unsigned tmp = 0u;
        if (t >= off) tmp = ls[t - off];
        __syncthreads();
        if (t >= off) ls[t] += tmp;
        __syncthreads();
    }
    bucketBase[t] = (t == 0) ? 0u : ls[t - 1];
}

__global__ __launch_bounds__(THREADS) void p2_partition(
    const float* __restrict__ nf,
    const int*   __restrict__ srcs,
    const int*   __restrict__ dsts,
    const float* __restrict__ cm,
    const float* __restrict__ Wp, const float* __restrict__ bp,
    const float* __restrict__ msp, const float* __restrict__ cpp_,
    const unsigned int* __restrict__ relT,        // scanned histT
    const unsigned int* __restrict__ bucketBase,
    uint2* __restrict__ recs, int E, int epb)
{
    __shared__ unsigned int cur[NBUCK];      // block's running global cursor / bucket
    __shared__ unsigned int hist[NBUCK];
    __shared__ unsigned int exclS[NBUCK];    // within-tile exclusive offsets
    __shared__ unsigned int rankCur[NBUCK];  // mutable rank cursors (pass 2)
    __shared__ unsigned int scanT[NBUCK];
    __shared__ uint2 buf[TILE];              // 32 KB bucket-sorted record buffer

    const int blk = blockIdx.x;
    const int t   = threadIdx.x;
    if (t < NBUCK)
        cur[t] = bucketBase[t] + relT[(size_t)t * NBLK + blk];

    const float W0 = Wp[0], W1 = Wp[1], W2 = Wp[2];
    const float bb = bp[0], ms = msp[0], cp = cpp_[0];

    const int start = blk * epb;
    const int end   = min(E, start + epb);

    for (int t0 = start; t0 < end; t0 += TILE) {
        const int n    = min(end - t0, TILE);
        const int nvec = n >> 2;

        // --- pass 1: tile histogram of dst ---
        if (t < NBUCK) hist[t] = 0u;
        __syncthreads();
        for (int i = t; i < nvec; i += THREADS) {
            const int4 d4 = *(const int4*)(dsts + t0 + (i << 2));
            atomicAdd(&hist[d4.x >> BSH], 1u);
            atomicAdd(&hist[d4.y >> BSH], 1u);
            atomicAdd(&hist[d4.z >> BSH], 1u);
            atomicAdd(&hist[d4.w >> BSH], 1u);
        }
        for (int e = t0 + (nvec << 2) + t; e < t0 + n; e += THREADS)
            atomicAdd(&hist[dsts[e] >> BSH], 1u);
        __syncthreads();

        // --- inclusive scan over 128 buckets (barrier by all threads) ---
        if (t < NBUCK) scanT[t] = hist[t];
        __syncthreads();
        for (int off = 1; off < NBUCK; off <<= 1) {
            unsigned v = 0u;
            if (t < NBUCK && t >= off) v = scanT[t - off];
            __syncthreads();
            if (t < NBUCK && t >= off) scanT[t] += v;
            __syncthreads();
        }
        if (t < NBUCK) {
            const unsigned e = scanT[t] - hist[t];   // exclusive
            exclS[t]   = e;
            rankCur[t] = e;
        }
        __syncthreads();

        // --- pass 2: recompute msg, rank, permute into LDS (dst tile is L1-hot) ---
        for (int i = t; i < nvec; i += THREADS) {
            const int base = t0 + (i << 2);
            const int4   s4 = *(const int4*)  (srcs + base);
            const int4   d4 = *(const int4*)  (dsts + base);
            const float4 c4 = *(const float4*)(cm   + base);
            const int   s[4] = {s4.x, s4.y, s4.z, s4.w};
            const int   d[4] = {d4.x, d4.y, d4.z, d4.w};
            const float c[4] = {c4.x, c4.y, c4.z, c4.w};
#pragma unroll
            for (int k = 0; k < 4; ++k) {
                const float msg = edge_msg(nf[s[k]], nf[d[k]], c[k],
                                           W0, W1, W2, bb, ms, cp);
                const unsigned r = atomicAdd(&rankCur[d[k] >> BSH], 1u);
                buf[r] = make_uint2(__float_as_uint(msg), (unsigned)d[k]);
            }
        }
        for (int e = t0 + (nvec << 2) + t; e < t0 + n; e += THREADS) {
            const float msg = edge_msg(nf[srcs[e]], nf[dsts[e]], cm[e],
                                       W0, W1, W2, bb, ms, cp);
            const unsigned r = atomicAdd(&rankCur[dsts[e] >> BSH], 1u);
            buf[r] = make_uint2(__float_as_uint(msg), (unsigned)dsts[e]);
        }
        __syncthreads();

        // --- coalesced copy-out: consecutive j in a bucket -> consecutive pos ---
        for (int j = t; j < n; j += THREADS) {
            const uint2 r = buf[j];
            const unsigned b = r.y >> BSH;
            recs[cur[b] + (unsigned)j - exclS[b]] = r;
        }
        __syncthreads();
        if (t < NBUCK) cur[t] += hist[t];
        __syncthreads();
    }
}

__global__ __launch_bounds__(THREADS) void p3_reduce(
    const uint2* __restrict__ recs,
    const unsigned int* __restrict__ totals,
    const unsigned int* __restrict__ bucketBase,
    float* __restrict__ partials)            // [NSLICE][NPAD]
{
    __shared__ float acc[NPB];               // 32 KB
    const int b = blockIdx.x / NSLICE;
    const int s = blockIdx.x % NSLICE;
    const int t = threadIdx.x;

    for (int j = t; j < NPB; j += THREADS) acc[j] = 0.0f;
    __syncthreads();

    const unsigned cnt   = totals[b];
    const unsigned base  = bucketBase[b];
    const unsigned chunk = (cnt + NSLICE - 1) / NSLICE;
    unsigned k0 = min(cnt, s * chunk);
    unsigned k1 = min(cnt, k0 + chunk);
    unsigned g0 = base + k0, g1 = base + k1;

    // scalar head/tail so the main loop runs 16 B-aligned uint4 (2 records)
    if ((g0 & 1u) && g0 < g1) {
        if (t == 0) {
            const uint2 r = recs[g0];
            atomicAdd(&acc[r.y & (NPB - 1u)], __uint_as_float(r.x));
        }
        ++g0;
    }
    if (g0 < g1 && ((g1 - g0) & 1u)) {
        --g1;
        if (t == 0) {
            const uint2 r = recs[g1];
            atomicAdd(&acc[r.y & (NPB - 1u)], __uint_as_float(r.x));
        }
    }
    const unsigned np = (g1 > g0) ? ((g1 - g0) >> 1) : 0u;
    for (unsigned p = t; p < np; p += THREADS) {
        const uint4 q = *(const uint4*)(recs + g0 + (p << 1));
        atomicAdd(&acc[q.y & (NPB - 1u)], __uint_as_float(q.x));
        atomicAdd(&acc[q.w & (NPB - 1u)], __uint_as_float(q.z));
    }
    __syncthreads();

    // partial store (always, even for empty slices: ws is poisoned)
    float* dst = partials + (size_t)s * NPAD + ((size_t)b << BSH);
    for (int j = t << 2; j < NPB; j += THREADS << 2)
        *(float4*)(dst + j) = *(float4*)(acc + j);
}

__global__ __launch_bounds__(THREADS) void p4_sum(
    const float* __restrict__ partials, float* __restrict__ out, int N)
{
    const int b4 = (blockIdx.x * blockDim.x + threadIdx.x) << 2;
    if (b4 + 3 < N) {
        float4 a = *(const float4*)(partials + b4);
#pragma unroll
        for (int s = 1; s < NSLICE; ++s) {
            const float4 v = *(const float4*)(partials + (size_t)s * NPAD + b4);
            a.x += v.x; a.y += v.y; a.z += v.z; a.w += v.w;
        }
        *(float4*)(out + b4) = a;
    } else if (b4 < N) {
        for (int j = b4; j < N; ++j) {
            float a = 0.0f;
#pragma unroll
            for (int s = 0; s < NSLICE; ++s) a += partials[(size_t)s * NPAD + j];
            out[j] = a;
        }
    }
}

// ---- proven fallback (round-1 kernel) if ws is too small ----
__global__ __launch_bounds__(THREADS) void cagat_atomic_fallback(
    const float* __restrict__ nf, const int* __restrict__ srcs,
    const int* __restrict__ dsts, const float* __restrict__ cm,
    const float* __restrict__ Wp, const float* __restrict__ bp,
    const float* __restrict__ msp, const float* __restrict__ cpp_,
    float* __restrict__ out, int E)
{
    const float W0 = Wp[0], W1 = Wp[1], W2 = Wp[2];
    const float bb = bp[0], ms = msp[0], cp = cpp_[0];
    const int i = blockIdx.x * blockDim.x + threadIdx.x;
    for (int e = i; e < E; e += gridDim.x * blockDim.x) {
        const float msg = edge_msg(nf[srcs[e]], nf[dsts[e]], cm[e],
                                   W0, W1, W2, bb, ms, cp);
        atomicAdd(out + dsts[e], msg);
    }
}

extern "C" void kernel_launch(void* const* d_in, const int* in_sizes, int n_in,
                              void* d_out, int out_size, void* d_ws, size_t ws_size,
                              hipStream_t stream) {
    const float* nf   = (const float*)d_in[0];
    const int*   eidx = (const int*)  d_in[1];   // [2, E]: src row then dst row
    const float* cm   = (const float*)d_in[2];
    const float* W    = (const float*)d_in[3];
    const float* b    = (const float*)d_in[4];
    const float* ms   = (const float*)d_in[5];
    const float* cp   = (const float*)d_in[6];
    float*       out  = (float*)d_out;

    const int E = in_sizes[2];
    const int N = in_sizes[0];
    const int* srcs = eidx;
    const int* dsts = eidx + E;

    const size_t recs_bytes = (size_t)E * 8u;
    const size_t hist_bytes = (size_t)NBUCK * NBLK * 4u;
    const size_t tot_bytes  = 2u * (size_t)NBUCK * 4u;           // totals + base
    const size_t part_bytes = (size_t)NSLICE * NPAD * 4u;        // 16 MB
    const size_t need = recs_bytes + hist_bytes + tot_bytes + part_bytes;

    if (ws_size < need || N > NPAD) {
        hipMemsetAsync(d_out, 0, (size_t)out_size * sizeof(float), stream);
        cagat_atomic_fallback<<<8192, THREADS, 0, stream>>>(
            nf, srcs, dsts, cm, W, b, ms, cp, out, E);
        return;
    }

    char* wsb = (char*)d_ws;
    uint2*        recs       = (uint2*)wsb;
    unsigned int* histT      = (unsigned int*)(wsb + recs_bytes);
    unsigned int* totals     = (unsigned int*)(wsb + recs_bytes + hist_bytes);
    unsigned int* bucketBase = totals + NBUCK;
    float*        partials   = (float*)(wsb + recs_bytes + hist_bytes + tot_bytes);

    const int epb = (E + NBLK - 1) / NBLK;       // 32768 for E=2^25

    p1_hist<<<NBLK, THREADS, 0, stream>>>(dsts, E, epb, histT);
    p_scan1<<<NBUCK, THREADS, 0, stream>>>(histT, totals);
    p_scan2<<<1, NBUCK, 0, stream>>>(totals, bucketBase);
    p2_partition<<<NBLK, THREADS, 0, stream>>>(
        nf, srcs, dsts, cm, W, b, ms, cp, histT, bucketBase, recs, E, epb);
    p3_reduce<<<NBUCK * NSLICE, THREADS, 0, stream>>>(
        recs, totals, bucketBase, partials);
    p4_sum<<<(N + 4 * THREADS - 1) / (4 * THREADS), THREADS, 0, stream>>>(
        partials, out, N);
}